// Round 3
// baseline (415.800 us; speedup 1.0000x reference)
//
#include <hip/hip_runtime.h>

#define V_SIZE 50257
#define B_SIZE 256
#define S_LEN  15
#define H_DIM  512
#define NBLK_LG 786   // ceil(50257/64)

typedef __attribute__((ext_vector_type(8))) short bf16x8;
typedef __attribute__((ext_vector_type(4))) float f32x4;

__device__ __forceinline__ unsigned short f2bf(float f) {
    unsigned int u = __float_as_uint(f);
    u += 0x7fffu + ((u >> 16) & 1u);   // RNE
    return (unsigned short)(u >> 16);
}

// ---------------------------------------------------------------------------
// K1: u[b,n] = sum_o h[b,o] * attn_W[o,n]   (fp32 vector; 67 MMAC total)
// ---------------------------------------------------------------------------
__global__ __launch_bounds__(256) void u_kernel(
    const float* __restrict__ hidden, const float* __restrict__ attn_W,
    float* __restrict__ u)
{
    __shared__ float h_s[16][H_DIM];
    const int tid = threadIdx.x;
    const int b0 = blockIdx.y * 16, n0 = blockIdx.x * 32;
    const float4* hv = (const float4*)(hidden + (size_t)b0 * H_DIM);
    float4* hs4 = (float4*)&h_s[0][0];
    #pragma unroll
    for (int i = 0; i < 8; ++i) hs4[tid + i * 256] = hv[tid + i * 256];
    __syncthreads();
    const int n = n0 + (tid & 31);
    const int m = (tid >> 5) * 2;
    float a0 = 0.f, a1 = 0.f;
    #pragma unroll 8
    for (int o = 0; o < H_DIM; ++o) {
        float w = attn_W[(size_t)o * H_DIM + n];
        a0 += h_s[m][o] * w;
        a1 += h_s[m + 1][o] * w;
    }
    u[(size_t)(b0 + m) * H_DIM + n] = a0;
    u[(size_t)(b0 + m + 1) * H_DIM + n] = a1;
}

// ---------------------------------------------------------------------------
// K2: per-b attention + bf16 prep of x=[emb,ctx] and h
// ---------------------------------------------------------------------------
__global__ __launch_bounds__(256) void attn_kernel(
    const float* __restrict__ hidden, const float* __restrict__ enc,
    const float* __restrict__ u, const int* __restrict__ tokens,
    const float* __restrict__ emb, float* __restrict__ attnw_out,
    unsigned short* __restrict__ x_bf, unsigned short* __restrict__ h_bf)
{
    const int b = blockIdx.x, tid = threadIdx.x;
    __shared__ float u_s[H_DIM];
    __shared__ float sc_s[S_LEN];
    __shared__ float w_s[S_LEN];
    u_s[tid]       = u[(size_t)b * H_DIM + tid];
    u_s[tid + 256] = u[(size_t)b * H_DIM + tid + 256];
    h_bf[(size_t)b * H_DIM + tid]       = f2bf(hidden[(size_t)b * H_DIM + tid]);
    h_bf[(size_t)b * H_DIM + tid + 256] = f2bf(hidden[(size_t)b * H_DIM + tid + 256]);
    const int tok = tokens[b];
    x_bf[(size_t)b * 2 * H_DIM + tid]       = f2bf(emb[(size_t)tok * H_DIM + tid]);
    x_bf[(size_t)b * 2 * H_DIM + tid + 256] = f2bf(emb[(size_t)tok * H_DIM + tid + 256]);
    __syncthreads();
    const int wave = tid >> 6, lane = tid & 63;
    for (int s = wave; s < S_LEN; s += 4) {
        const float* e = enc + ((size_t)b * S_LEN + s) * H_DIM;
        float acc = 0.f;
        #pragma unroll
        for (int k = 0; k < H_DIM / 64; ++k) acc += e[lane + k * 64] * u_s[lane + k * 64];
        #pragma unroll
        for (int off = 32; off; off >>= 1) acc += __shfl_down(acc, off);
        if (lane == 0) sc_s[s] = acc;
    }
    __syncthreads();
    float mx = -1e30f;
    for (int s = 0; s < S_LEN; ++s) mx = fmaxf(mx, sc_s[s]);
    float sum = 0.f;
    for (int s = 0; s < S_LEN; ++s) sum += __expf(sc_s[s] - mx);
    const float inv = 1.f / sum;
    if (tid < S_LEN) {
        float w = __expf(sc_s[tid] - mx) * inv;
        w_s[tid] = w;
        attnw_out[b * S_LEN + tid] = w;
    }
    __syncthreads();
    #pragma unroll
    for (int hh = 0; hh < 2; ++hh) {
        int h = tid + hh * 256;
        float c = 0.f;
        #pragma unroll
        for (int s = 0; s < S_LEN; ++s)
            c += w_s[s] * enc[((size_t)b * S_LEN + s) * H_DIM + h];
        x_bf[(size_t)b * 2 * H_DIM + H_DIM + h] = f2bf(c);
    }
}

// ---------------------------------------------------------------------------
// NT MFMA GEMM with register-prefetch pipeline.
// C[M,N] = A[M,K](bf16) * B[N,K](f32->bf16)^T + bias
// PART: additionally emit per-(row, block) softmax partials (max, sumexp).
// ---------------------------------------------------------------------------
struct GemmP {
    const unsigned short* A; const float* B; const float* bias; float* C;
    int N; int K; float* pm; float* ps;
};

template<int BM, int BN, int BK, int WR, int WC, bool PART>
__global__ __launch_bounds__(256) void gemm_nt(GemmP p0, GemmP p1)
{
    GemmP p = (blockIdx.z == 0) ? p0 : p1;
    constexpr int LDA = BK + 24;  // 112B pitch @BK=32: 16B-aligned rows, 28-bank shift (conflict-free)
    __shared__ __align__(16) unsigned short As[BM][LDA];
    __shared__ __align__(16) unsigned short Bs[BN][LDA];
    const int tid = threadIdx.x;
    const int bn0 = blockIdx.x * BN;
    const int bm0 = blockIdx.y * BM;
    const int wave = tid >> 6, lane = tid & 63;
    const int wm = (wave / WC) * (BM / WR);
    const int wn = (wave % WC) * (BN / WC);
    constexpr int MF = BM / WR / 16, NF = BN / WC / 16;
    const int n16 = lane & 15, quad = lane >> 4;
    constexpr int SEG = BK / 8;               // 16B segments per row
    constexpr int IA = BM * SEG / 256;        // A uint4 per thread per tile
    constexpr int IB = BN * SEG / 256;        // B (2x float4) per thread per tile
    static_assert(IA >= 1 && IB >= 1, "tile too small");

    uint4 ra[IA];
    float4 rb0[IB], rb1[IB];

    auto loadA = [&](int k0) {
        #pragma unroll
        for (int it = 0; it < IA; ++it) {
            int v = it * 256 + tid;
            int row = v / SEG, seg = v % SEG;
            ra[it] = *(const uint4*)(p.A + (size_t)(bm0 + row) * p.K + k0 + seg * 8);
        }
    };
    auto loadB = [&](int k0) {
        #pragma unroll
        for (int it = 0; it < IB; ++it) {
            int v = it * 256 + tid;
            int row = v / SEG, seg = v % SEG;
            int gv = bn0 + row;
            float4 z; z.x = z.y = z.z = z.w = 0.f;
            rb0[it] = z; rb1[it] = z;
            if (gv < p.N) {
                const float4* src = (const float4*)(p.B + (size_t)gv * p.K + k0 + seg * 8);
                rb0[it] = src[0]; rb1[it] = src[1];
            }
        }
    };
    auto storeAB = [&]() {
        #pragma unroll
        for (int it = 0; it < IA; ++it) {
            int v = it * 256 + tid;
            int row = v / SEG, seg = v % SEG;
            *(uint4*)&As[row][seg * 8] = ra[it];
        }
        #pragma unroll
        for (int it = 0; it < IB; ++it) {
            int v = it * 256 + tid;
            int row = v / SEG, seg = v % SEG;
            uint4 pk;
            pk.x = (unsigned)f2bf(rb0[it].x) | ((unsigned)f2bf(rb0[it].y) << 16);
            pk.y = (unsigned)f2bf(rb0[it].z) | ((unsigned)f2bf(rb0[it].w) << 16);
            pk.z = (unsigned)f2bf(rb1[it].x) | ((unsigned)f2bf(rb1[it].y) << 16);
            pk.w = (unsigned)f2bf(rb1[it].z) | ((unsigned)f2bf(rb1[it].w) << 16);
            *(uint4*)&Bs[row][seg * 8] = pk;
        }
    };

    f32x4 acc[MF][NF] = {};
    loadA(0); loadB(0);
    for (int k0 = 0; k0 < p.K; k0 += BK) {
        storeAB();                              // waits vmcnt of prefetch here
        __syncthreads();
        if (k0 + BK < p.K) { loadA(k0 + BK); loadB(k0 + BK); }  // issue early
        #pragma unroll
        for (int kk = 0; kk < BK; kk += 32) {
            bf16x8 af[MF], bfr[NF];
            #pragma unroll
            for (int i = 0; i < MF; ++i)
                af[i] = *(const bf16x8*)&As[wm + i * 16 + n16][kk + quad * 8];
            #pragma unroll
            for (int j = 0; j < NF; ++j)
                bfr[j] = *(const bf16x8*)&Bs[wn + j * 16 + n16][kk + quad * 8];
            #pragma unroll
            for (int i = 0; i < MF; ++i)
                #pragma unroll
                for (int j = 0; j < NF; ++j)
                    acc[i][j] = __builtin_amdgcn_mfma_f32_16x16x32_bf16(
                        af[i], bfr[j], acc[i][j], 0, 0, 0);
        }
        __syncthreads();
    }

    // epilogue: C/D layout col = lane&15, row = quad*4 + reg
    int cj[NF]; float bvv[NF]; bool okj[NF];
    #pragma unroll
    for (int j = 0; j < NF; ++j) {
        cj[j] = bn0 + wn + j * 16 + n16;
        okj[j] = cj[j] < p.N;
        bvv[j] = okj[j] ? p.bias[cj[j]] : 0.f;
    }
    #pragma unroll
    for (int i = 0; i < MF; ++i) {
        const int r0 = bm0 + wm + i * 16 + quad * 4;
        if (PART) {
            #pragma unroll
            for (int r = 0; r < 4; ++r) {
                float m = -1e30f;
                #pragma unroll
                for (int j = 0; j < NF; ++j)
                    if (okj[j]) m = fmaxf(m, acc[i][j][r] + bvv[j]);
                #pragma unroll
                for (int d = 1; d < 16; d <<= 1) m = fmaxf(m, __shfl_xor(m, d));
                float s = 0.f;
                #pragma unroll
                for (int j = 0; j < NF; ++j)
                    if (okj[j]) s += __expf(acc[i][j][r] + bvv[j] - m);
                #pragma unroll
                for (int d = 1; d < 16; d <<= 1) s += __shfl_xor(s, d);
                if (n16 == 0) {
                    int row = r0 + r;
                    p.pm[(size_t)row * NBLK_LG + blockIdx.x] = m;
                    p.ps[(size_t)row * NBLK_LG + blockIdx.x] = s;
                }
            }
        }
        #pragma unroll
        for (int j = 0; j < NF; ++j) if (okj[j]) {
            #pragma unroll
            for (int r = 0; r < 4; ++r)
                p.C[(size_t)(r0 + r) * p.N + cj[j]] = acc[i][j][r] + bvv[j];
        }
    }
}

// ---------------------------------------------------------------------------
// K3c: GRU gate math (fp32), writes h_new (f32 to d_out) + bf16 copy for GEMM
// ---------------------------------------------------------------------------
__global__ __launch_bounds__(256) void gru_kernel(
    const float* __restrict__ gi, const float* __restrict__ gh,
    const float* __restrict__ hidden, float* __restrict__ hnew_out,
    unsigned short* __restrict__ hnew_bf)
{
    const int idx = blockIdx.x * 256 + threadIdx.x;   // < 131072
    const int b = idx >> 9, h = idx & 511;
    const float* gib = gi + (size_t)b * 3 * H_DIM;
    const float* ghb = gh + (size_t)b * 3 * H_DIM;
    float r = 1.f / (1.f + __expf(-(gib[h] + ghb[h])));
    float z = 1.f / (1.f + __expf(-(gib[H_DIM + h] + ghb[H_DIM + h])));
    float n = gib[2 * H_DIM + h] + r * ghb[2 * H_DIM + h];
    n = 1.f - 2.f / (1.f + __expf(2.f * n));          // tanh
    float hp = hidden[idx];
    float hn = (1.f - z) * n + z * hp;
    hnew_out[idx] = hn;
    hnew_bf[idx] = f2bf(hn);
}

// ---------------------------------------------------------------------------
// K5 (fused path): combine 786 partials/row -> lse, then one subtract pass
// ---------------------------------------------------------------------------
__global__ __launch_bounds__(1024) void finalize_kernel(
    float* __restrict__ logits, const float* __restrict__ pm,
    const float* __restrict__ ps)
{
    const int b = blockIdx.x, tid = threadIdx.x;
    float m = -1e30f, s = 0.f;
    for (int i = tid; i < NBLK_LG; i += 1024) {
        float mm = pm[(size_t)b * NBLK_LG + i], ss = ps[(size_t)b * NBLK_LG + i];
        float nm = fmaxf(m, mm);
        s = s * __expf(m - nm) + ss * __expf(mm - nm);
        m = nm;
    }
    const int lane = tid & 63, wave = tid >> 6;
    #pragma unroll
    for (int off = 32; off; off >>= 1) {
        float m2 = __shfl_down(m, off), s2 = __shfl_down(s, off);
        float nm = fmaxf(m, m2);
        s = s * __expf(m - nm) + s2 * __expf(m2 - nm);
        m = nm;
    }
    __shared__ float msh[16], ssh[16], lse_sh;
    if (lane == 0) { msh[wave] = m; ssh[wave] = s; }
    __syncthreads();
    if (tid == 0) {
        float M = msh[0], S = ssh[0];
        for (int w = 1; w < 16; ++w) {
            float nm = fmaxf(M, msh[w]);
            S = S * __expf(M - nm) + ssh[w] * __expf(msh[w] - nm);
            M = nm;
        }
        lse_sh = M + logf(S);
    }
    __syncthreads();
    const float lse = lse_sh;
    float* row = logits + (size_t)b * V_SIZE;
    const int pre = (4 - (b & 3)) & 3;        // align to 16B (V odd -> rows drift)
    if ((int)tid < pre) row[tid] -= lse;
    const int nv = (V_SIZE - pre) >> 2;
    float4* r4 = (float4*)(row + pre);
    for (int i = tid; i < nv; i += 1024) {
        float4 v = r4[i];
        v.x -= lse; v.y -= lse; v.z -= lse; v.w -= lse;
        r4[i] = v;
    }
    const int ts = pre + nv * 4;
    if (ts + (int)tid < V_SIZE) row[ts + tid] -= lse;
}

// ---------------------------------------------------------------------------
// K5 (fallback): classic two-pass log-softmax (if ws too small for partials)
// ---------------------------------------------------------------------------
__global__ __launch_bounds__(1024) void logsoftmax_kernel(float* __restrict__ logits)
{
    const int b = blockIdx.x, tid = threadIdx.x;
    float* row = logits + (size_t)b * V_SIZE;
    float m = -1e30f, s = 0.f;
    for (int c = tid; c < V_SIZE; c += 1024) {
        float x = row[c];
        float nm = fmaxf(m, x);
        s = s * __expf(m - nm) + __expf(x - nm);
        m = nm;
    }
    const int lane = tid & 63, wave = tid >> 6;
    #pragma unroll
    for (int off = 32; off; off >>= 1) {
        float m2 = __shfl_down(m, off), s2 = __shfl_down(s, off);
        float nm = fmaxf(m, m2);
        s = s * __expf(m - nm) + s2 * __expf(m2 - nm);
        m = nm;
    }
    __shared__ float msh[16], ssh[16], lse_sh;
    if (lane == 0) { msh[wave] = m; ssh[wave] = s; }
    __syncthreads();
    if (tid == 0) {
        float M = msh[0], S = ssh[0];
        for (int w = 1; w < 16; ++w) {
            float nm = fmaxf(M, msh[w]);
            S = S * __expf(M - nm) + ssh[w] * __expf(msh[w] - nm);
            M = nm;
        }
        lse_sh = M + logf(S);
    }
    __syncthreads();
    const float lse = lse_sh;
    for (int c = tid; c < V_SIZE; c += 1024) row[c] -= lse;
}

// ---------------------------------------------------------------------------
// workspace layout (bytes)
// ---------------------------------------------------------------------------
constexpr size_t OFF_U      = 0;         // 256*512*4  = 524288
constexpr size_t OFF_XBF    = 524288;    // 256*1024*2 = 524288
constexpr size_t OFF_HBF    = 1048576;   // 256*512*2  = 262144
constexpr size_t OFF_HNEWBF = 1310720;   // 262144
constexpr size_t OFF_GI     = 1572864;   // 256*1536*4 = 1572864
constexpr size_t OFF_GH     = 3145728;   // 1572864
constexpr size_t OFF_PM     = 4718592;   // 256*786*4  = 804864
constexpr size_t OFF_PS     = 5523456;   // 804864
constexpr size_t WS_NEED    = 6328320;

extern "C" void kernel_launch(void* const* d_in, const int* in_sizes, int n_in,
                              void* d_out, int out_size, void* d_ws, size_t ws_size,
                              hipStream_t stream) {
    const int*   tokens = (const int*)d_in[0];
    const float* hidden = (const float*)d_in[1];
    const float* enc    = (const float*)d_in[2];
    const float* emb    = (const float*)d_in[3];
    const float* attn_W = (const float*)d_in[4];
    // d_in[5] = attn_b: constant across s -> cancels in softmax; unused
    const float* W_ih   = (const float*)d_in[6];
    const float* W_hh   = (const float*)d_in[7];
    const float* b_ih   = (const float*)d_in[8];
    const float* b_hh   = (const float*)d_in[9];
    const float* out_W  = (const float*)d_in[10];
    const float* out_b  = (const float*)d_in[11];

    float* out = (float*)d_out;
    float* logp      = out;                                   // [256][50257]
    float* hnew_out  = out + (size_t)B_SIZE * V_SIZE;         // [256][512]
    float* attnw_out = hnew_out + (size_t)B_SIZE * H_DIM;     // [256][15]

    char* ws = (char*)d_ws;
    float*          u_ws    = (float*)(ws + OFF_U);
    unsigned short* x_bf    = (unsigned short*)(ws + OFF_XBF);
    unsigned short* h_bf    = (unsigned short*)(ws + OFF_HBF);
    unsigned short* hnew_bf = (unsigned short*)(ws + OFF_HNEWBF);
    float*          gi_ws   = (float*)(ws + OFF_GI);
    float*          gh_ws   = (float*)(ws + OFF_GH);
    float*          pm_ws   = (float*)(ws + OFF_PM);
    float*          ps_ws   = (float*)(ws + OFF_PS);

    u_kernel<<<dim3(16, 16), 256, 0, stream>>>(hidden, attn_W, u_ws);
    attn_kernel<<<dim3(256), 256, 0, stream>>>(hidden, enc, u_ws, tokens, emb,
                                               attnw_out, x_bf, h_bf);
    GemmP gi_p { x_bf, W_ih, b_ih, gi_ws, 3 * H_DIM, 2 * H_DIM, nullptr, nullptr };
    GemmP gh_p { h_bf, W_hh, b_hh, gh_ws, 3 * H_DIM, H_DIM, nullptr, nullptr };
    gemm_nt<64, 64, 32, 2, 2, false><<<dim3(24, 4, 2), 256, 0, stream>>>(gi_p, gh_p);
    gru_kernel<<<dim3(512), 256, 0, stream>>>(gi_ws, gh_ws, hidden, hnew_out, hnew_bf);

    if (ws_size >= WS_NEED) {
        GemmP lg { hnew_bf, out_W, out_b, logp, V_SIZE, H_DIM, pm_ws, ps_ws };
        gemm_nt<256, 64, 32, 4, 1, true><<<dim3(NBLK_LG, 1, 1), 256, 0, stream>>>(lg, lg);
        finalize_kernel<<<dim3(256), 1024, 0, stream>>>(logp, pm_ws, ps_ws);
    } else {
        GemmP lg { hnew_bf, out_W, out_b, logp, V_SIZE, H_DIM, nullptr, nullptr };
        gemm_nt<256, 64, 32, 4, 1, false><<<dim3(NBLK_LG, 1, 1), 256, 0, stream>>>(lg, lg);
        logsoftmax_kernel<<<dim3(256), 1024, 0, stream>>>(logp);
    }
}

// Round 4
// 372.938 us; speedup vs baseline: 1.1149x; 1.1149x over previous
//
#include <hip/hip_runtime.h>

#define V_SIZE 50257
#define B_SIZE 256
#define S_LEN  15
#define H_DIM  512
#define NBLK_LG 786   // ceil(50257/64)

typedef __attribute__((ext_vector_type(8))) short bf16x8;
typedef __attribute__((ext_vector_type(4))) float f32x4;

__device__ __forceinline__ unsigned short f2bf(float f) {
    unsigned int u = __float_as_uint(f);
    u += 0x7fffu + ((u >> 16) & 1u);   // RNE
    return (unsigned short)(u >> 16);
}

// ---------------------------------------------------------------------------
// K1: u[b,n] = sum_o h[b,o] * attn_W[o,n]   (fp32 vector; 67 MMAC total)
// ---------------------------------------------------------------------------
__global__ __launch_bounds__(256) void u_kernel(
    const float* __restrict__ hidden, const float* __restrict__ attn_W,
    float* __restrict__ u)
{
    __shared__ float h_s[16][H_DIM];
    const int tid = threadIdx.x;
    const int b0 = blockIdx.y * 16, n0 = blockIdx.x * 32;
    const float4* hv = (const float4*)(hidden + (size_t)b0 * H_DIM);
    float4* hs4 = (float4*)&h_s[0][0];
    #pragma unroll
    for (int i = 0; i < 8; ++i) hs4[tid + i * 256] = hv[tid + i * 256];
    __syncthreads();
    const int n = n0 + (tid & 31);
    const int m = (tid >> 5) * 2;
    float a0 = 0.f, a1 = 0.f;
    #pragma unroll 8
    for (int o = 0; o < H_DIM; ++o) {
        float w = attn_W[(size_t)o * H_DIM + n];
        a0 += h_s[m][o] * w;
        a1 += h_s[m + 1][o] * w;
    }
    u[(size_t)(b0 + m) * H_DIM + n] = a0;
    u[(size_t)(b0 + m + 1) * H_DIM + n] = a1;
}

// ---------------------------------------------------------------------------
// K2: per-b attention + bf16 prep of x=[emb,ctx] and h
// ---------------------------------------------------------------------------
__global__ __launch_bounds__(256) void attn_kernel(
    const float* __restrict__ hidden, const float* __restrict__ enc,
    const float* __restrict__ u, const int* __restrict__ tokens,
    const float* __restrict__ emb, float* __restrict__ attnw_out,
    unsigned short* __restrict__ x_bf, unsigned short* __restrict__ h_bf)
{
    const int b = blockIdx.x, tid = threadIdx.x;
    __shared__ float u_s[H_DIM];
    __shared__ float sc_s[S_LEN];
    __shared__ float w_s[S_LEN];
    u_s[tid]       = u[(size_t)b * H_DIM + tid];
    u_s[tid + 256] = u[(size_t)b * H_DIM + tid + 256];
    h_bf[(size_t)b * H_DIM + tid]       = f2bf(hidden[(size_t)b * H_DIM + tid]);
    h_bf[(size_t)b * H_DIM + tid + 256] = f2bf(hidden[(size_t)b * H_DIM + tid + 256]);
    const int tok = tokens[b];
    x_bf[(size_t)b * 2 * H_DIM + tid]       = f2bf(emb[(size_t)tok * H_DIM + tid]);
    x_bf[(size_t)b * 2 * H_DIM + tid + 256] = f2bf(emb[(size_t)tok * H_DIM + tid + 256]);
    __syncthreads();
    const int wave = tid >> 6, lane = tid & 63;
    for (int s = wave; s < S_LEN; s += 4) {
        const float* e = enc + ((size_t)b * S_LEN + s) * H_DIM;
        float acc = 0.f;
        #pragma unroll
        for (int k = 0; k < H_DIM / 64; ++k) acc += e[lane + k * 64] * u_s[lane + k * 64];
        #pragma unroll
        for (int off = 32; off; off >>= 1) acc += __shfl_down(acc, off);
        if (lane == 0) sc_s[s] = acc;
    }
    __syncthreads();
    float mx = -1e30f;
    for (int s = 0; s < S_LEN; ++s) mx = fmaxf(mx, sc_s[s]);
    float sum = 0.f;
    for (int s = 0; s < S_LEN; ++s) sum += __expf(sc_s[s] - mx);
    const float inv = 1.f / sum;
    if (tid < S_LEN) {
        float w = __expf(sc_s[tid] - mx) * inv;
        w_s[tid] = w;
        attnw_out[b * S_LEN + tid] = w;
    }
    __syncthreads();
    #pragma unroll
    for (int hh = 0; hh < 2; ++hh) {
        int h = tid + hh * 256;
        float c = 0.f;
        #pragma unroll
        for (int s = 0; s < S_LEN; ++s)
            c += w_s[s] * enc[((size_t)b * S_LEN + s) * H_DIM + h];
        x_bf[(size_t)b * 2 * H_DIM + H_DIM + h] = f2bf(c);
    }
}

// ---------------------------------------------------------------------------
// Small NT MFMA GEMM (exact R2 structure): C = A(bf16) * B(f32->bf16)^T + bias
// ---------------------------------------------------------------------------
struct GemmP {
    const unsigned short* A; const float* B; const float* bias; float* C;
    int N; int K;
};

template<int BM, int BN, int BK, int WR, int WC>
__global__ __launch_bounds__(256) void gemm_nt(GemmP p0, GemmP p1)
{
    GemmP p = (blockIdx.z == 0) ? p0 : p1;
    constexpr int LDA = BK + 8;
    __shared__ __align__(16) unsigned short As[BM][LDA];
    __shared__ __align__(16) unsigned short Bs[BN][LDA];
    const int tid = threadIdx.x;
    const int bn0 = blockIdx.x * BN;
    const int bm0 = blockIdx.y * BM;
    const int wave = tid >> 6, lane = tid & 63;
    const int wm = (wave / WC) * (BM / WR);
    const int wn = (wave % WC) * (BN / WC);
    constexpr int MF = BM / WR / 16, NF = BN / WC / 16;
    const int n16 = lane & 15, quad = lane >> 4;

    f32x4 acc[MF][NF] = {};

    for (int k0 = 0; k0 < p.K; k0 += BK) {
        #pragma unroll
        for (int it = 0; it < BM / 32; ++it) {
            int v = it * 256 + tid;
            int row = v >> 3, seg = v & 7;
            *(uint4*)&As[row][seg * 8] =
                *(const uint4*)(p.A + (size_t)(bm0 + row) * p.K + k0 + seg * 8);
        }
        #pragma unroll
        for (int it = 0; it < BN / 32; ++it) {
            int v = it * 256 + tid;
            int row = v >> 3, seg = v & 7;
            int gv = bn0 + row;
            float4 w0 = make_float4(0, 0, 0, 0), w1 = make_float4(0, 0, 0, 0);
            if (gv < p.N) {
                const float4* src = (const float4*)(p.B + (size_t)gv * p.K + k0 + seg * 8);
                w0 = src[0]; w1 = src[1];
            }
            uint4 pk;
            pk.x = (unsigned)f2bf(w0.x) | ((unsigned)f2bf(w0.y) << 16);
            pk.y = (unsigned)f2bf(w0.z) | ((unsigned)f2bf(w0.w) << 16);
            pk.z = (unsigned)f2bf(w1.x) | ((unsigned)f2bf(w1.y) << 16);
            pk.w = (unsigned)f2bf(w1.z) | ((unsigned)f2bf(w1.w) << 16);
            *(uint4*)&Bs[row][seg * 8] = pk;
        }
        __syncthreads();
        #pragma unroll
        for (int kk = 0; kk < BK; kk += 32) {
            bf16x8 af[MF], bfr[NF];
            #pragma unroll
            for (int i = 0; i < MF; ++i)
                af[i] = *(const bf16x8*)&As[wm + i * 16 + n16][kk + quad * 8];
            #pragma unroll
            for (int j = 0; j < NF; ++j)
                bfr[j] = *(const bf16x8*)&Bs[wn + j * 16 + n16][kk + quad * 8];
            #pragma unroll
            for (int i = 0; i < MF; ++i)
                #pragma unroll
                for (int j = 0; j < NF; ++j)
                    acc[i][j] = __builtin_amdgcn_mfma_f32_16x16x32_bf16(
                        af[i], bfr[j], acc[i][j], 0, 0, 0);
        }
        __syncthreads();
    }
    #pragma unroll
    for (int i = 0; i < MF; ++i) {
        const int r0 = bm0 + wm + i * 16 + quad * 4;
        #pragma unroll
        for (int j = 0; j < NF; ++j) {
            const int c = bn0 + wn + j * 16 + n16;
            if (c < p.N) {
                const float bv = p.bias[c];
                #pragma unroll
                for (int r = 0; r < 4; ++r)
                    p.C[(size_t)(r0 + r) * p.N + c] = acc[i][j][r] + bv;
            }
        }
    }
}

// ---------------------------------------------------------------------------
// Logits GEMM: C[256, V] = hnew_bf[256,512] @ out_W[V,512]^T + out_b.
// BM=256 (full M, grid.y=1), BN=64, BK=128, WR=4/WC=1.
// Key: A rows are wave-private -> A fragments load DIRECTLY from global (L2),
// no A LDS, no A barrier. Only B staged in LDS (shared by all 4 waves).
// LDS = 64*136*2 = 17.4 KB -> 4 blocks/CU. 8 barriers total (4 k-iters).
// PART: emits per-(row,block) softmax partials, per-block-CONTIGUOUS layout
// pm[block*256+row] (R3's [row][block] scatter caused +114MB write ampl).
// ---------------------------------------------------------------------------
template<bool PART>
__global__ __launch_bounds__(256, 4) void gemm_lg(
    const unsigned short* __restrict__ A, const float* __restrict__ B,
    const float* __restrict__ bias, float* __restrict__ C,
    float* __restrict__ pm, float* __restrict__ ps)
{
    constexpr int BN = 64, BK = 128;
    constexpr int LDB = BK + 8;              // 136 shorts = 272B pitch
    __shared__ __align__(16) unsigned short Bs[BN][LDB];
    const int tid = threadIdx.x;
    const int bn0 = blockIdx.x * BN;
    const int wave = tid >> 6, lane = tid & 63;
    const int wm = wave * 64;                 // wave-private 64 A-rows
    const int n16 = lane & 15, quad = lane >> 4;

    f32x4 acc[4][4] = {};
    // per-lane A row base pointers (constant over K loop)
    const unsigned short* arow[4];
    #pragma unroll
    for (int i = 0; i < 4; ++i) arow[i] = A + (size_t)(wm + i * 16 + n16) * H_DIM;

    for (int k0 = 0; k0 < H_DIM; k0 += BK) {
        // stage B: 64 rows x 128 k (f32) -> bf16 LDS. 1024 v-slots of 8 f32.
        #pragma unroll
        for (int it = 0; it < 4; ++it) {
            int v = it * 256 + tid;
            int row = v >> 4, seg = v & 15;
            int gv = bn0 + row;
            float4 w0 = make_float4(0, 0, 0, 0), w1 = make_float4(0, 0, 0, 0);
            if (gv < V_SIZE) {
                const float4* src = (const float4*)(B + (size_t)gv * H_DIM + k0 + seg * 8);
                w0 = src[0]; w1 = src[1];
            }
            uint4 pk;
            pk.x = (unsigned)f2bf(w0.x) | ((unsigned)f2bf(w0.y) << 16);
            pk.y = (unsigned)f2bf(w0.z) | ((unsigned)f2bf(w0.w) << 16);
            pk.z = (unsigned)f2bf(w1.x) | ((unsigned)f2bf(w1.y) << 16);
            pk.w = (unsigned)f2bf(w1.z) | ((unsigned)f2bf(w1.w) << 16);
            *(uint4*)&Bs[row][seg * 8] = pk;
        }
        __syncthreads();
        #pragma unroll
        for (int kk = 0; kk < BK; kk += 32) {
            bf16x8 af[4], bfr[4];
            #pragma unroll
            for (int i = 0; i < 4; ++i)
                af[i] = *(const bf16x8*)(arow[i] + k0 + kk + quad * 8);  // global, L2-hit
            #pragma unroll
            for (int j = 0; j < 4; ++j)
                bfr[j] = *(const bf16x8*)&Bs[j * 16 + n16][kk + quad * 8];
            #pragma unroll
            for (int i = 0; i < 4; ++i)
                #pragma unroll
                for (int j = 0; j < 4; ++j)
                    acc[i][j] = __builtin_amdgcn_mfma_f32_16x16x32_bf16(
                        af[i], bfr[j], acc[i][j], 0, 0, 0);
        }
        __syncthreads();
    }

    // epilogue
    int cj[4]; float bvv[4]; bool okj[4];
    #pragma unroll
    for (int j = 0; j < 4; ++j) {
        cj[j] = bn0 + j * 16 + n16;
        okj[j] = cj[j] < V_SIZE;
        bvv[j] = okj[j] ? bias[cj[j]] : 0.f;
    }
    #pragma unroll
    for (int i = 0; i < 4; ++i) {
        const int r0 = wm + i * 16 + quad * 4;
        if (PART) {
            #pragma unroll
            for (int r = 0; r < 4; ++r) {
                float m = -1e30f;
                #pragma unroll
                for (int j = 0; j < 4; ++j)
                    if (okj[j]) m = fmaxf(m, acc[i][j][r] + bvv[j]);
                #pragma unroll
                for (int d = 1; d < 16; d <<= 1) m = fmaxf(m, __shfl_xor(m, d));
                float s = 0.f;
                #pragma unroll
                for (int j = 0; j < 4; ++j)
                    if (okj[j]) s += __expf(acc[i][j][r] + bvv[j] - m);
                #pragma unroll
                for (int d = 1; d < 16; d <<= 1) s += __shfl_xor(s, d);
                if (n16 == 0) {
                    // per-block-contiguous: block's 256 dwords in one 1KB span
                    pm[(size_t)blockIdx.x * B_SIZE + r0 + r] = m;
                    ps[(size_t)blockIdx.x * B_SIZE + r0 + r] = s;
                }
            }
        }
        #pragma unroll
        for (int j = 0; j < 4; ++j) if (okj[j]) {
            #pragma unroll
            for (int r = 0; r < 4; ++r)
                C[(size_t)(r0 + r) * V_SIZE + cj[j]] = acc[i][j][r] + bvv[j];
        }
    }
}

// ---------------------------------------------------------------------------
// K3c: GRU gate math (fp32), writes h_new (f32 to d_out) + bf16 copy for GEMM
// ---------------------------------------------------------------------------
__global__ __launch_bounds__(256) void gru_kernel(
    const float* __restrict__ gi, const float* __restrict__ gh,
    const float* __restrict__ hidden, float* __restrict__ hnew_out,
    unsigned short* __restrict__ hnew_bf)
{
    const int idx = blockIdx.x * 256 + threadIdx.x;   // < 131072
    const int b = idx >> 9, h = idx & 511;
    const float* gib = gi + (size_t)b * 3 * H_DIM;
    const float* ghb = gh + (size_t)b * 3 * H_DIM;
    float r = 1.f / (1.f + __expf(-(gib[h] + ghb[h])));
    float z = 1.f / (1.f + __expf(-(gib[H_DIM + h] + ghb[H_DIM + h])));
    float n = gib[2 * H_DIM + h] + r * ghb[2 * H_DIM + h];
    n = 1.f - 2.f / (1.f + __expf(2.f * n));          // tanh
    float hp = hidden[idx];
    float hn = (1.f - z) * n + z * hp;
    hnew_out[idx] = hn;
    hnew_bf[idx] = f2bf(hn);
}

// ---------------------------------------------------------------------------
// K5: combine 786 partials/row -> lse, subtract over this block's V-half.
// grid (256 rows, 2 halves), block 1024
// ---------------------------------------------------------------------------
__global__ __launch_bounds__(1024) void finalize_kernel(
    float* __restrict__ logits, const float* __restrict__ pm,
    const float* __restrict__ ps)
{
    const int b = blockIdx.x, tid = threadIdx.x;
    float m = -1e30f, s = 0.f;
    for (int i = tid; i < NBLK_LG; i += 1024) {
        float mm = pm[(size_t)i * B_SIZE + b], ss = ps[(size_t)i * B_SIZE + b];
        float nm = fmaxf(m, mm);
        s = s * __expf(m - nm) + ss * __expf(mm - nm);
        m = nm;
    }
    const int lane = tid & 63, wave = tid >> 6;
    #pragma unroll
    for (int off = 32; off; off >>= 1) {
        float m2 = __shfl_down(m, off), s2 = __shfl_down(s, off);
        float nm = fmaxf(m, m2);
        s = s * __expf(m - nm) + s2 * __expf(m2 - nm);
        m = nm;
    }
    __shared__ float msh[16], ssh[16], lse_sh;
    if (lane == 0) { msh[wave] = m; ssh[wave] = s; }
    __syncthreads();
    if (tid == 0) {
        float M = msh[0], S = ssh[0];
        for (int w = 1; w < 16; ++w) {
            float nm = fmaxf(M, msh[w]);
            S = S * __expf(M - nm) + ssh[w] * __expf(msh[w] - nm);
            M = nm;
        }
        lse_sh = M + logf(S);
    }
    __syncthreads();
    const float lse = lse_sh;
    constexpr int HALF = (V_SIZE + 1) / 2;    // 25129
    const int start = blockIdx.y * HALF;
    const int end = min(V_SIZE, start + HALF);
    float* row = logits + (size_t)b * V_SIZE;
    for (int c = start + tid; c < end; c += 1024) row[c] -= lse;
}

// fallback: two-pass log-softmax (only if ws too small for partials)
__global__ __launch_bounds__(1024) void logsoftmax_kernel(float* __restrict__ logits)
{
    const int b = blockIdx.x, tid = threadIdx.x;
    float* row = logits + (size_t)b * V_SIZE;
    float m = -1e30f, s = 0.f;
    for (int c = tid; c < V_SIZE; c += 1024) {
        float x = row[c];
        float nm = fmaxf(m, x);
        s = s * __expf(m - nm) + __expf(x - nm);
        m = nm;
    }
    const int lane = tid & 63, wave = tid >> 6;
    #pragma unroll
    for (int off = 32; off; off >>= 1) {
        float m2 = __shfl_down(m, off), s2 = __shfl_down(s, off);
        float nm = fmaxf(m, m2);
        s = s * __expf(m - nm) + s2 * __expf(m2 - nm);
        m = nm;
    }
    __shared__ float msh[16], ssh[16], lse_sh;
    if (lane == 0) { msh[wave] = m; ssh[wave] = s; }
    __syncthreads();
    if (tid == 0) {
        float M = msh[0], S = ssh[0];
        for (int w = 1; w < 16; ++w) {
            float nm = fmaxf(M, msh[w]);
            S = S * __expf(M - nm) + ssh[w] * __expf(msh[w] - nm);
            M = nm;
        }
        lse_sh = M + logf(S);
    }
    __syncthreads();
    const float lse = lse_sh;
    for (int c = tid; c < V_SIZE; c += 1024) row[c] -= lse;
}

// ---------------------------------------------------------------------------
// workspace layout (bytes)
// ---------------------------------------------------------------------------
constexpr size_t OFF_U      = 0;         // 256*512*4  = 524288
constexpr size_t OFF_XBF    = 524288;    // 256*1024*2 = 524288
constexpr size_t OFF_HBF    = 1048576;   // 256*512*2  = 262144
constexpr size_t OFF_HNEWBF = 1310720;   // 262144
constexpr size_t OFF_GI     = 1572864;   // 256*1536*4 = 1572864
constexpr size_t OFF_GH     = 3145728;   // 1572864
constexpr size_t OFF_PM     = 4718592;   // 786*256*4  = 804864
constexpr size_t OFF_PS     = 5523456;   // 804864
constexpr size_t WS_NEED    = 6328320;

extern "C" void kernel_launch(void* const* d_in, const int* in_sizes, int n_in,
                              void* d_out, int out_size, void* d_ws, size_t ws_size,
                              hipStream_t stream) {
    const int*   tokens = (const int*)d_in[0];
    const float* hidden = (const float*)d_in[1];
    const float* enc    = (const float*)d_in[2];
    const float* emb    = (const float*)d_in[3];
    const float* attn_W = (const float*)d_in[4];
    // d_in[5] = attn_b: constant across s -> cancels in softmax; unused
    const float* W_ih   = (const float*)d_in[6];
    const float* W_hh   = (const float*)d_in[7];
    const float* b_ih   = (const float*)d_in[8];
    const float* b_hh   = (const float*)d_in[9];
    const float* out_W  = (const float*)d_in[10];
    const float* out_b  = (const float*)d_in[11];

    float* out = (float*)d_out;
    float* logp      = out;                                   // [256][50257]
    float* hnew_out  = out + (size_t)B_SIZE * V_SIZE;         // [256][512]
    float* attnw_out = hnew_out + (size_t)B_SIZE * H_DIM;     // [256][15]

    char* ws = (char*)d_ws;
    float*          u_ws    = (float*)(ws + OFF_U);
    unsigned short* x_bf    = (unsigned short*)(ws + OFF_XBF);
    unsigned short* h_bf    = (unsigned short*)(ws + OFF_HBF);
    unsigned short* hnew_bf = (unsigned short*)(ws + OFF_HNEWBF);
    float*          gi_ws   = (float*)(ws + OFF_GI);
    float*          gh_ws   = (float*)(ws + OFF_GH);
    float*          pm_ws   = (float*)(ws + OFF_PM);
    float*          ps_ws   = (float*)(ws + OFF_PS);

    u_kernel<<<dim3(16, 16), 256, 0, stream>>>(hidden, attn_W, u_ws);
    attn_kernel<<<dim3(256), 256, 0, stream>>>(hidden, enc, u_ws, tokens, emb,
                                               attnw_out, x_bf, h_bf);
    GemmP gi_p { x_bf, W_ih, b_ih, gi_ws, 3 * H_DIM, 2 * H_DIM };
    GemmP gh_p { h_bf, W_hh, b_hh, gh_ws, 3 * H_DIM, H_DIM };
    gemm_nt<64, 64, 64, 2, 2><<<dim3(24, 4, 2), 256, 0, stream>>>(gi_p, gh_p);
    gru_kernel<<<dim3(512), 256, 0, stream>>>(gi_ws, gh_ws, hidden, hnew_out, hnew_bf);

    if (ws_size >= WS_NEED) {
        gemm_lg<true><<<dim3(NBLK_LG), 256, 0, stream>>>(
            hnew_bf, out_W, out_b, logp, pm_ws, ps_ws);
        finalize_kernel<<<dim3(256, 2), 1024, 0, stream>>>(logp, pm_ws, ps_ws);
    } else {
        gemm_lg<false><<<dim3(NBLK_LG), 256, 0, stream>>>(
            hnew_bf, out_W, out_b, logp, nullptr, nullptr);
        logsoftmax_kernel<<<dim3(256), 1024, 0, stream>>>(logp);
    }
}